// Round 1
// 232.370 us; speedup vs baseline: 1.8859x; 1.8859x over previous
//
#include <hip/hip_runtime.h>
#include <math.h>

#define B_ 8
#define C_ 128
#define N_ 16384
#define SCALE_ 0.17677669529663687f
#define EPS_ 1e-5f

#define KV_STRIDE 36    // k/v tiles [128][36] fp32 (ctx kernel)
#define XU_STRIDE 68    // packed f16-pair (uint) tile stride
#define REC_ 4224       // per-block record: 4096 P + 128 S

typedef _Float16 half8 __attribute__((ext_vector_type(8)));
typedef float floatx4 __attribute__((ext_vector_type(4)));

static __device__ inline unsigned short f16bits(float v) {
  _Float16 h = (_Float16)v;
  return __builtin_bit_cast(unsigned short, h);
}

// pack two floats into one hi-pair uint and one lo-pair uint (split-f16)
static __device__ inline void pack2(float a0, float a1,
                                    unsigned int& hp, unsigned int& lp) {
  _Float16 h0 = (_Float16)a0;
  _Float16 h1 = (_Float16)a1;
  float l0f = (a0 - (float)h0) * 2048.0f;
  float l1f = (a1 - (float)h1) * 2048.0f;
  hp = ((unsigned int)__builtin_bit_cast(unsigned short, h1) << 16) |
       (unsigned int)__builtin_bit_cast(unsigned short, h0);
  lp = ((unsigned int)f16bits(l1f) << 16) | (unsigned int)f16bits(l0f);
}

static __device__ inline void split8(const float* p, half8& hi, half8& lo) {
  float4 f0 = *(const float4*)p;
  float4 f1 = *(const float4*)(p + 4);
  float fv[8] = {f0.x, f0.y, f0.z, f0.w, f1.x, f1.y, f1.z, f1.w};
#pragma unroll
  for (int j = 0; j < 8; ++j) {
    _Float16 hj = (_Float16)fv[j];
    hi[j] = hj;
    lo[j] = (_Float16)((fv[j] - (float)hj) * 2048.0f);
  }
}

// ---------------------------------------------------------------------------
// Kernel 1: k/v GEMM via split-f16 MFMA, exp(k); P accumulated via MFMA
// (head = wave) across all chunks, S accumulated in registers.
// grid = B_ * bpb, block = 256
// ---------------------------------------------------------------------------
__global__ __launch_bounds__(256, 2) void lin_attn_ctx(
    const float* __restrict__ x, const float* __restrict__ wqkv,
    float* __restrict__ Ws)
{
  __shared__ __align__(16) unsigned int xhiu[32 * XU_STRIDE];
  __shared__ __align__(16) unsigned int xlou[32 * XU_STRIDE];
  __shared__ __align__(16) float ks[128 * KV_STRIDE];
  __shared__ __align__(16) float vs[128 * KV_STRIDE];

  const int t = threadIdx.x;
  const int bpb = gridDim.x / B_;
  const int b = blockIdx.x / bpb;
  const int blk = blockIdx.x - b * bpb;
  const int nchunks = 512 / bpb;
  const int pbase = blk * (nchunks << 5);

  const int lane = t & 63;
  const int wave = t >> 6;
  const int l15 = lane & 15;
  const int quad = lane >> 4;

  // persistent A fragments: k|v weight rows (wqkv rows 128..383)
  half8 ahi[4][4], alo[4][4];
#pragma unroll
  for (int r = 0; r < 4; ++r) {
#pragma unroll
    for (int s = 0; s < 4; ++s) {
      const int m = (wave << 6) + (r << 4) + l15;
      split8(wqkv + (size_t)(128 + m) * C_ + (s << 5) + (quad << 3),
             ahi[r][s], alo[r][s]);
    }
  }

  // per-wave P accumulators (head = wave), 32x32 as 2x2 MFMA tiles
  floatx4 pacc1[2][2], pacc2[2][2];
#pragma unroll
  for (int i = 0; i < 2; ++i)
#pragma unroll
    for (int j = 0; j < 2; ++j) {
      pacc1[i][j] = (floatx4){0.f, 0.f, 0.f, 0.f};
      pacc2[i][j] = (floatx4){0.f, 0.f, 0.f, 0.f};
    }
  float sacc[16];
#pragma unroll
  for (int u = 0; u < 16; ++u) sacc[u] = 0.f;

  const float* xb = x + ((size_t)b * C_) * N_;
  const int kp0 = t >> 3;            // 0..31
  const int pq0 = (t & 7) << 2;      // 0,4,..,28

  // register prefetch of chunk 0 (rows 2*kp0, 2*kp0+1, +64, +65)
  float4 fa0, fa1, fb0, fb1;
  {
    const float* p = xb + pbase + pq0;
    fa0 = *(const float4*)(p + (size_t)(2 * kp0) * N_);
    fa1 = *(const float4*)(p + (size_t)(2 * kp0 + 1) * N_);
    fb0 = *(const float4*)(p + (size_t)(2 * kp0 + 64) * N_);
    fb1 = *(const float4*)(p + (size_t)(2 * kp0 + 65) * N_);
  }

  for (int c4 = 0; c4 < nchunks; ++c4) {
    __syncthreads();   // prior chunk's xhiu / ks / vs reads done
    // ---- stage x chunk (from prefetched regs) as packed f16 hi/lo ----
    {
      float a0[4] = {fa0.x, fa0.y, fa0.z, fa0.w};
      float a1[4] = {fa1.x, fa1.y, fa1.z, fa1.w};
      float c0[4] = {fb0.x, fb0.y, fb0.z, fb0.w};
      float c1[4] = {fb1.x, fb1.y, fb1.z, fb1.w};
#pragma unroll
      for (int j = 0; j < 4; ++j) {
        unsigned int hp, lp;
        pack2(a0[j], a1[j], hp, lp);
        xhiu[(pq0 + j) * XU_STRIDE + kp0] = hp;
        xlou[(pq0 + j) * XU_STRIDE + kp0] = lp;
        pack2(c0[j], c1[j], hp, lp);
        xhiu[(pq0 + j) * XU_STRIDE + kp0 + 32] = hp;
        xlou[(pq0 + j) * XU_STRIDE + kp0 + 32] = lp;
      }
    }
    __syncthreads();
    // issue next chunk's global loads; latency hides under GEMM + P phase
    if (c4 + 1 < nchunks) {
      const float* p = xb + pbase + ((c4 + 1) << 5) + pq0;
      fa0 = *(const float4*)(p + (size_t)(2 * kp0) * N_);
      fa1 = *(const float4*)(p + (size_t)(2 * kp0 + 1) * N_);
      fb0 = *(const float4*)(p + (size_t)(2 * kp0 + 64) * N_);
      fb1 = *(const float4*)(p + (size_t)(2 * kp0 + 65) * N_);
    }

    // ---- main k/v GEMM ----
    floatx4 acc1[4][2], acc2[4][2];
#pragma unroll
    for (int r = 0; r < 4; ++r)
#pragma unroll
      for (int c = 0; c < 2; ++c) {
        acc1[r][c] = (floatx4){0.f, 0.f, 0.f, 0.f};
        acc2[r][c] = (floatx4){0.f, 0.f, 0.f, 0.f};
      }
    __builtin_amdgcn_s_setprio(1);
#pragma unroll
    for (int s = 0; s < 4; ++s) {
#pragma unroll
      for (int c = 0; c < 2; ++c) {
        int off = ((c << 4) + l15) * XU_STRIDE + (s << 4) + (quad << 2);
        half8 bh = __builtin_bit_cast(half8, *(const uint4*)&xhiu[off]);
        half8 bl = __builtin_bit_cast(half8, *(const uint4*)&xlou[off]);
#pragma unroll
        for (int r = 0; r < 4; ++r) {
          acc1[r][c] = __builtin_amdgcn_mfma_f32_16x16x32_f16(ahi[r][s], bh, acc1[r][c], 0, 0, 0);
          acc2[r][c] = __builtin_amdgcn_mfma_f32_16x16x32_f16(ahi[r][s], bl, acc2[r][c], 0, 0, 0);
          acc2[r][c] = __builtin_amdgcn_mfma_f32_16x16x32_f16(alo[r][s], bh, acc2[r][c], 0, 0, 0);
        }
      }
    }
    __builtin_amdgcn_s_setprio(0);

    // ---- write exp(k) | v to LDS; accumulate S in registers (k waves) ----
    if (wave < 2) {
#pragma unroll
      for (int r = 0; r < 4; ++r)
#pragma unroll
        for (int c = 0; c < 2; ++c) {
          int px = (c << 4) + l15;
#pragma unroll
          for (int reg = 0; reg < 4; ++reg) {
            float val = acc1[r][c][reg] + acc2[r][c][reg] * (1.0f / 2048.0f);
            int row = (wave << 6) + (r << 4) + (quad << 2) + reg;   // 0..127
            float e = __expf(val);
            ks[row * KV_STRIDE + px] = e;
            sacc[r * 4 + reg] += e;
          }
        }
    } else {
#pragma unroll
      for (int r = 0; r < 4; ++r)
#pragma unroll
        for (int c = 0; c < 2; ++c) {
          int px = (c << 4) + l15;
#pragma unroll
          for (int reg = 0; reg < 4; ++reg) {
            float val = acc1[r][c][reg] + acc2[r][c][reg] * (1.0f / 2048.0f);
            int row = (wave << 6) + (r << 4) + (quad << 2) + reg - 128; // 0..127
            vs[row * KV_STRIDE + px] = val;
          }
        }
    }
    __syncthreads();

    // ---- P update via MFMA: head h = wave, P_h += ek_h * v_h^T over 32 px ----
    {
      half8 eh[2], el[2], vh[2], vl[2];
#pragma unroll
      for (int tt = 0; tt < 2; ++tt) {
        split8(&ks[(wave * 32 + tt * 16 + l15) * KV_STRIDE + (quad << 3)], eh[tt], el[tt]);
        split8(&vs[(wave * 32 + tt * 16 + l15) * KV_STRIDE + (quad << 3)], vh[tt], vl[tt]);
      }
      __builtin_amdgcn_s_setprio(1);
#pragma unroll
      for (int at = 0; at < 2; ++at)
#pragma unroll
        for (int bt = 0; bt < 2; ++bt) {
          pacc1[at][bt] = __builtin_amdgcn_mfma_f32_16x16x32_f16(eh[at], vh[bt], pacc1[at][bt], 0, 0, 0);
          pacc2[at][bt] = __builtin_amdgcn_mfma_f32_16x16x32_f16(eh[at], vl[bt], pacc2[at][bt], 0, 0, 0);
          pacc2[at][bt] = __builtin_amdgcn_mfma_f32_16x16x32_f16(el[at], vh[bt], pacc2[at][bt], 0, 0, 0);
        }
      __builtin_amdgcn_s_setprio(0);
    }
  }

  // ---- epilogue: per-block record {P[4096], S[128]} ----
  {
    float* rec = Ws + (size_t)blockIdx.x * REC_;
#pragma unroll
    for (int at = 0; at < 2; ++at)
#pragma unroll
      for (int bt = 0; bt < 2; ++bt)
#pragma unroll
        for (int reg = 0; reg < 4; ++reg) {
          int dk = at * 16 + (quad << 2) + reg;
          int dv = bt * 16 + l15;
          rec[((wave * 32 + dk) << 5) + dv] =
              pacc1[at][bt][reg] + pacc2[at][bt][reg] * (1.0f / 2048.0f);
        }
    if (wave < 2) {
#pragma unroll
      for (int u = 0; u < 16; ++u) {
        float s = sacc[u];
        s += __shfl_xor(s, 1);
        s += __shfl_xor(s, 2);
        s += __shfl_xor(s, 4);
        s += __shfl_xor(s, 8);
        sacc[u] = s;
      }
      if (l15 == 0) {
#pragma unroll
        for (int r = 0; r < 4; ++r)
#pragma unroll
          for (int reg = 0; reg < 4; ++reg)
            rec[4096 + (wave << 6) + (r << 4) + (quad << 2) + reg] = sacc[r * 4 + reg];
      }
    }
  }
}

// ---------------------------------------------------------------------------
// Reduction: sum `slots` records per batch -> final P[b][4096], S[b][128]
// grid = 132, block = 256
// ---------------------------------------------------------------------------
__global__ void lin_attn_reduce(const float* __restrict__ Ws, int slots,
                                float* __restrict__ Pf, float* __restrict__ Sf)
{
  int idx = blockIdx.x * 256 + threadIdx.x;
  int b = idx / REC_;
  int j = idx - b * REC_;
  const float* src = Ws + (size_t)b * slots * REC_ + j;
  float s0 = 0.f, s1 = 0.f, s2 = 0.f, s3 = 0.f;
  for (int k = 0; k < slots; k += 4) {
    s0 += src[(size_t)(k + 0) * REC_];
    s1 += src[(size_t)(k + 1) * REC_];
    s2 += src[(size_t)(k + 2) * REC_];
    s3 += src[(size_t)(k + 3) * REC_];
  }
  float s = (s0 + s1) + (s2 + s3);
  if (j < 4096) Pf[b * 4096 + j] = s;
  else          Sf[b * 128 + (j - 4096)] = s;
}

// ---------------------------------------------------------------------------
// G[b][o][h*32+dk] = SCALE * sum_dv wout[o][h*32+dv] * ctx_h[dk][dv],
// ctx_h[dk][dv] = P[h][dk][dv] / (S[h*32+dk] * N).  grid = B_*64, block = 256
// ---------------------------------------------------------------------------
__global__ void lin_attn_gmat(const float* __restrict__ Pf,
                              const float* __restrict__ Sf,
                              const float* __restrict__ wout,
                              float* __restrict__ G)
{
  __shared__ float ctxs[4096];
  const int t = threadIdx.x;
  const int b = blockIdx.x >> 6;
  const int o0 = (blockIdx.x & 63) << 1;
#pragma unroll
  for (int i = 0; i < 16; ++i) {
    int lin = t + 256 * i;
    ctxs[lin] = Pf[b * 4096 + lin] / (Sf[b * 128 + (lin >> 5)] * 16384.f);
  }
  __syncthreads();
  const int o = o0 + (t >> 7);
  const int col = t & 127;
  const int h = col >> 5, dk = col & 31;
  const float* wrow = wout + (size_t)o * 128 + h * 32;
  const float* crow = &ctxs[h * 1024 + dk * 32];
  float s = 0.f;
#pragma unroll
  for (int q = 0; q < 8; ++q) {
    float4 w4 = *(const float4*)&wrow[q * 4];
    float4 c4 = *(const float4*)&crow[q * 4];
    s += w4.x * c4.x + w4.y * c4.y + w4.z * c4.z + w4.w * c4.w;
  }
  G[(size_t)b * 16384 + (size_t)o * 128 + col] = s * SCALE_;
}

// ---------------------------------------------------------------------------
// Kernel 2: per 32-px chunk: q = w_q*x (MFMA) -> IN-REGISTER head softmax
// (tree + shfl_xor over quads) -> packed qhat emit -> y = G*qhat (MFMA) ->
// in-register LN partials + tiny LDS cross-wave reduce. grid = B_*64
// ---------------------------------------------------------------------------
__global__ __launch_bounds__(256, 2) void lin_attn_out(
    const float* __restrict__ x, const float* __restrict__ wqkv,
    const float* __restrict__ G, const float* __restrict__ bout,
    const float* __restrict__ alpha, const float* __restrict__ beta,
    float* __restrict__ out)
{
  __shared__ __align__(16) unsigned int xhiu[32 * XU_STRIDE];
  __shared__ __align__(16) unsigned int xlou[32 * XU_STRIDE];
  __shared__ __align__(16) unsigned int qhiu[32 * XU_STRIDE];
  __shared__ __align__(16) unsigned int qlou[32 * XU_STRIDE];
  __shared__ float red_s[128];
  __shared__ float red_q[128];

  const int t = threadIdx.x;
  const int bpb = gridDim.x / B_;
  const int b = blockIdx.x / bpb;
  const int blk = blockIdx.x - b * bpb;
  const int nchunks = 512 / bpb;
  const int pbase = blk * (nchunks << 5);

  const int lane = t & 63;
  const int wave = t >> 6;                // head / channel group [wave*32,+32)
  const int l15 = lane & 15;
  const int quad = lane >> 4;

  // persistent A fragments: w_q rows and G rows [wave*32, +32)
  half8 qhiA[2][4], qloA[2][4], ghiA[2][4], gloA[2][4];
#pragma unroll
  for (int r = 0; r < 2; ++r) {
#pragma unroll
    for (int s = 0; s < 4; ++s) {
      const int m = (wave << 5) + (r << 4) + l15;
      split8(wqkv + (size_t)m * C_ + (s << 5) + (quad << 3), qhiA[r][s], qloA[r][s]);
      split8(G + (size_t)b * 16384 + (size_t)m * 128 + (s << 5) + (quad << 3),
             ghiA[r][s], gloA[r][s]);
    }
  }

  // per-lane channel constants: ch = wave*32 + r*16 + quad*4 + reg
  float bch[8], ach[8], bech[8];
#pragma unroll
  for (int r = 0; r < 2; ++r)
#pragma unroll
    for (int reg = 0; reg < 4; ++reg) {
      int ch = (wave << 5) + (r << 4) + (quad << 2) + reg;
      bch[r * 4 + reg] = bout[ch];
      ach[r * 4 + reg] = alpha[ch];
      bech[r * 4 + reg] = beta[ch];
    }

  const float* xb = x + ((size_t)b * C_) * N_;
  const int kp0 = t >> 3;
  const int pq0 = (t & 7) << 2;
  float4 fa0, fa1, fb0, fb1;
  {
    const float* p = xb + pbase + pq0;
    fa0 = *(const float4*)(p + (size_t)(2 * kp0) * N_);
    fa1 = *(const float4*)(p + (size_t)(2 * kp0 + 1) * N_);
    fb0 = *(const float4*)(p + (size_t)(2 * kp0 + 64) * N_);
    fb1 = *(const float4*)(p + (size_t)(2 * kp0 + 65) * N_);
  }

  for (int c4 = 0; c4 < nchunks; ++c4) {
    __syncthreads();   // protects xhiu (q GEMM), qhiu (y GEMM), red_s reads
    {
      float a0[4] = {fa0.x, fa0.y, fa0.z, fa0.w};
      float a1[4] = {fa1.x, fa1.y, fa1.z, fa1.w};
      float c0[4] = {fb0.x, fb0.y, fb0.z, fb0.w};
      float c1[4] = {fb1.x, fb1.y, fb1.z, fb1.w};
#pragma unroll
      for (int j = 0; j < 4; ++j) {
        unsigned int hp, lp;
        pack2(a0[j], a1[j], hp, lp);
        xhiu[(pq0 + j) * XU_STRIDE + kp0] = hp;
        xlou[(pq0 + j) * XU_STRIDE + kp0] = lp;
        pack2(c0[j], c1[j], hp, lp);
        xhiu[(pq0 + j) * XU_STRIDE + kp0 + 32] = hp;
        xlou[(pq0 + j) * XU_STRIDE + kp0 + 32] = lp;
      }
    }
    __syncthreads();
    if (c4 + 1 < nchunks) {
      const float* p = xb + pbase + ((c4 + 1) << 5) + pq0;
      fa0 = *(const float4*)(p + (size_t)(2 * kp0) * N_);
      fa1 = *(const float4*)(p + (size_t)(2 * kp0 + 1) * N_);
      fb0 = *(const float4*)(p + (size_t)(2 * kp0 + 64) * N_);
      fb1 = *(const float4*)(p + (size_t)(2 * kp0 + 65) * N_);
    }

    // ---- q GEMM ----
    floatx4 a1a[2][2], a2a[2][2];
#pragma unroll
    for (int r = 0; r < 2; ++r)
#pragma unroll
      for (int c = 0; c < 2; ++c) {
        a1a[r][c] = (floatx4){0.f, 0.f, 0.f, 0.f};
        a2a[r][c] = (floatx4){0.f, 0.f, 0.f, 0.f};
      }
    __builtin_amdgcn_s_setprio(1);
#pragma unroll
    for (int s = 0; s < 4; ++s) {
#pragma unroll
      for (int c = 0; c < 2; ++c) {
        int off = ((c << 4) + l15) * XU_STRIDE + (s << 4) + (quad << 2);
        half8 bh = __builtin_bit_cast(half8, *(const uint4*)&xhiu[off]);
        half8 bl = __builtin_bit_cast(half8, *(const uint4*)&xlou[off]);
#pragma unroll
        for (int r = 0; r < 2; ++r) {
          a1a[r][c] = __builtin_amdgcn_mfma_f32_16x16x32_f16(qhiA[r][s], bh, a1a[r][c], 0, 0, 0);
          a2a[r][c] = __builtin_amdgcn_mfma_f32_16x16x32_f16(qhiA[r][s], bl, a2a[r][c], 0, 0, 0);
          a2a[r][c] = __builtin_amdgcn_mfma_f32_16x16x32_f16(qloA[r][s], bh, a2a[r][c], 0, 0, 0);
        }
      }
    }
    __builtin_amdgcn_s_setprio(0);

    // ---- in-register head softmax (head = wave; reduce over {r,reg} in-lane
    //      and over quad via shfl_xor 16/32), emit packed qhat ----
#pragma unroll
    for (int c = 0; c < 2; ++c) {
      float qv[8];
#pragma unroll
      for (int r = 0; r < 2; ++r)
#pragma unroll
        for (int reg = 0; reg < 4; ++reg)
          qv[r * 4 + reg] = a1a[r][c][reg] + a2a[r][c][reg] * (1.0f / 2048.0f);
      float mx = fmaxf(fmaxf(fmaxf(qv[0], qv[1]), fmaxf(qv[2], qv[3])),
                       fmaxf(fmaxf(qv[4], qv[5]), fmaxf(qv[6], qv[7])));
      mx = fmaxf(mx, __shfl_xor(mx, 16));
      mx = fmaxf(mx, __shfl_xor(mx, 32));
      float e[8];
#pragma unroll
      for (int j = 0; j < 8; ++j) e[j] = __expf(qv[j] - mx);
      float ss = ((e[0] + e[1]) + (e[2] + e[3])) + ((e[4] + e[5]) + (e[6] + e[7]));
      ss += __shfl_xor(ss, 16);
      ss += __shfl_xor(ss, 32);
      float inv = 1.0f / ss;   // scale folded into G
      int px = (c << 4) + l15;
#pragma unroll
      for (int r = 0; r < 2; ++r) {
        unsigned int h0, l0, h1, l1;
        pack2(e[r * 4 + 0] * inv, e[r * 4 + 1] * inv, h0, l0);
        pack2(e[r * 4 + 2] * inv, e[r * 4 + 3] * inv, h1, l1);
        int kp = (wave << 4) + (r << 3) + (quad << 1);
        uint2 hu; hu.x = h0; hu.y = h1;
        uint2 lu; lu.x = l0; lu.y = l1;
        *(uint2*)&qhiu[px * XU_STRIDE + kp] = hu;
        *(uint2*)&qlou[px * XU_STRIDE + kp] = lu;
      }
    }
    __syncthreads();

    // ---- y GEMM: y = G * qhat ----
#pragma unroll
    for (int r = 0; r < 2; ++r)
#pragma unroll
      for (int c = 0; c < 2; ++c) {
        a1a[r][c] = (floatx4){0.f, 0.f, 0.f, 0.f};
        a2a[r][c] = (floatx4){0.f, 0.f, 0.f, 0.f};
      }
    __builtin_amdgcn_s_setprio(1);
#pragma unroll
    for (int s = 0; s < 4; ++s) {
#pragma unroll
      for (int c = 0; c < 2; ++c) {
        int off = ((c << 4) + l15) * XU_STRIDE + (s << 4) + (quad << 2);
        half8 bh = __builtin_bit_cast(half8, *(const uint4*)&qhiu[off]);
        half8 bl = __builtin_bit_cast(half8, *(const uint4*)&qlou[off]);
#pragma unroll
        for (int r = 0; r < 2; ++r) {
          a1a[r][c] = __builtin_amdgcn_mfma_f32_16x16x32_f16(ghiA[r][s], bh, a1a[r][c], 0, 0, 0);
          a2a[r][c] = __builtin_amdgcn_mfma_f32_16x16x32_f16(ghiA[r][s], bl, a2a[r][c], 0, 0, 0);
          a2a[r][c] = __builtin_amdgcn_mfma_f32_16x16x32_f16(gloA[r][s], bh, a2a[r][c], 0, 0, 0);
        }
      }
    }
    __builtin_amdgcn_s_setprio(0);

    // ---- LayerNorm: in-lane + quad partials, LDS only for 4-wave combine ----
#pragma unroll
    for (int c = 0; c < 2; ++c) {
      float sm = 0.f, sq = 0.f;
#pragma unroll
      for (int r = 0; r < 2; ++r)
#pragma unroll
        for (int reg = 0; reg < 4; ++reg) {
          float v = a1a[r][c][reg] + a2a[r][c][reg] * (1.0f / 2048.0f) + bch[r * 4 + reg];
          sm += v;
          sq += v * v;
        }
      sm += __shfl_xor(sm, 16);  sq += __shfl_xor(sq, 16);
      sm += __shfl_xor(sm, 32);  sq += __shfl_xor(sq, 32);
      if (quad == 0) {
        red_s[(wave << 5) + (c << 4) + l15] = sm;
        red_q[(wave << 5) + (c << 4) + l15] = sq;
      }
    }
    __syncthreads();
    {
      float* ob = out + ((size_t)b * C_) * N_ + pbase + (c4 << 5);
#pragma unroll
      for (int c = 0; c < 2; ++c) {
        int px = (c << 4) + l15;
        float ts = red_s[px] + red_s[32 + px] + red_s[64 + px] + red_s[96 + px];
        float tq = red_q[px] + red_q[32 + px] + red_q[64 + px] + red_q[96 + px];
        float mean = ts * (1.f / 128.f);
        float var = tq * (1.f / 128.f) - mean * mean;
        float rstd = 1.f / sqrtf(var + EPS_);
#pragma unroll
        for (int r = 0; r < 2; ++r)
#pragma unroll
          for (int reg = 0; reg < 4; ++reg) {
            int ch = (wave << 5) + (r << 4) + (quad << 2) + reg;
            float v = a1a[r][c][reg] + a2a[r][c][reg] * (1.0f / 2048.0f) + bch[r * 4 + reg];
            ob[(size_t)ch * N_ + px] = (v - mean) * rstd * ach[r * 4 + reg] + bech[r * 4 + reg];
          }
      }
    }
  }
}

extern "C" void kernel_launch(void* const* d_in, const int* in_sizes, int n_in,
                              void* d_out, int out_size, void* d_ws, size_t ws_size,
                              hipStream_t stream) {
  const float* x     = (const float*)d_in[0];
  const float* wqkv  = (const float*)d_in[1];
  const float* wout  = (const float*)d_in[2];
  const float* bout  = (const float*)d_in[3];
  const float* alpha = (const float*)d_in[4];
  const float* beta  = (const float*)d_in[5];
  float* outp = (float*)d_out;

  // workspace layout: G | Pf | Sf | records
  float* G  = (float*)d_ws;                          // [B][128][128]
  float* Pf = G + (size_t)B_ * 16384;                // [B][4096]
  float* Sf = Pf + (size_t)B_ * 4096;                // [B][128]
  float* Ws = Sf + (size_t)B_ * 128;                 // [B*bpb][4224]

  size_t need64 = ((size_t)B_ * 16384 + B_ * 4096 + B_ * 128 +
                   (size_t)B_ * 64 * REC_) * sizeof(float);
  int bpb_ctx = (ws_size >= need64) ? 64 : 32;

  lin_attn_ctx<<<dim3(B_ * bpb_ctx), dim3(256), 0, stream>>>(x, wqkv, Ws);
  lin_attn_reduce<<<dim3(132), dim3(256), 0, stream>>>(Ws, bpb_ctx, Pf, Sf);
  lin_attn_gmat<<<dim3(B_ * 64), dim3(256), 0, stream>>>(Pf, Sf, wout, G);
  lin_attn_out<<<dim3(B_ * 64), dim3(256), 0, stream>>>(x, wqkv, G, bout,
                                                        alpha, beta, outp);
}